// Round 1
// 5445.271 us; speedup vs baseline: 1.3437x; 1.3437x over previous
//
#include <hip/hip_runtime.h>
#include <math.h>

// LNN: BS=16384, d=32 (n=16), HID=512. All fp32.
// H = W1 D1 W1^T + M D2 M^T,  M = (W1^T diag(s1)) W2,  jac = W1 (s1*u),
// u = W2 (W3*s2), e1 = u(1-s1)/s1 so term1 = ws1T^T diag(e1) ws1T.
// out[:, :16] = qd = x[:,16:]; out[:,16:] = pinv(A) rhs  (fp64 Jacobi eig, JAX rcond).
//
// R1: occupancy restructure. LDS 81.8KB -> 31.9KB (2 -> 4 blocks/CU):
//  - ws1T never fully materialized: staged in 16KB quarters from a
//    pre-transposed W1T (d_ws), scaled by s1 on the fly (bit-identical values).
//  - M materialized in 16.9KB column-quarter passes ([32][132]), each wave
//    writing its own register panel; term2 accumulated in ascending q order
//    (bit-identical).
//  - P3 shuffle-reduce given 2-way ILP (two independent j chains).
// All accumulation orders match the previous passing kernel exactly.

#define NSWEEP 5
#define JAX_RCOND 1.9073486e-5   // 10 * 16 * eps_f32

#define MQS 132                   // M quarter row stride (floats), 33 float4s

// LDS float offsets
#define OFF_R    0                 // wsQ[128][32] / MQ[32][132] / fp64 Jacobi ws
#define R_FLOATS 4224
#define OFF_S1   (OFF_R + R_FLOATS)
#define OFF_H1   (OFF_S1+512)      // h1, later e1
#define OFF_G2   (OFF_H1+512)      // g2, later jac partials [16][16]
#define OFF_D2   (OFF_G2+512)
#define OFF_U    (OFF_D2+512)
#define OFF_X    (OFF_U+512)
#define OFF_JAC  (OFF_X+32)
#define OFF_T1   (OFF_JAC+16)      // [16][33]
#define OFF_T2   (OFF_T1+528)      // [16][33]
#define OFF_AUG  (OFF_T2+528)      // [16][17]
#define SMEM_FLOATS (OFF_AUG+272)
#define SMEM_BYTES  (SMEM_FLOATS*4)   // 32640 B -> 4 blocks/CU (reg-capped at 128/thread)

__device__ __forceinline__ void pairpq(int r, int m, int& p, int& q) {
    p = (m == 0) ? 0 : 1 + (m - 1 + r) % 15;
    q = 1 + (14 - m + r) % 15;
}

__device__ __forceinline__ void wave_fence() {
    __builtin_amdgcn_wave_barrier();
    __builtin_amdgcn_s_waitcnt(0);     // drain vm/exp/lgkm; DS ops of a wave retire in order
    __builtin_amdgcn_wave_barrier();
}

// Pre-kernel: W1T[j*32+i] = W1[i*512+j]   (64 KB, L2-resident afterwards)
extern "C" __global__ void w1_transpose(const float* __restrict__ W1,
                                        float* __restrict__ W1T) {
    const int t = blockIdx.x * 256 + threadIdx.x;   // t = j*32 + i
    W1T[t] = W1[(t & 31) * 512 + (t >> 5)];
}

extern "C" __global__ __launch_bounds__(256, 4)
void lnn_kernel(const float* __restrict__ x,
                const float* __restrict__ W1,
                const float* __restrict__ W1T,
                const float* __restrict__ b1,
                const float* __restrict__ W2, const float* __restrict__ b2,
                const float* __restrict__ W3,
                float* __restrict__ out)
{
    const int b = blockIdx.x;
    const int t = threadIdx.x;
    const int lane = t & 63;
    const int w = t >> 6;

    extern __shared__ float sm[];
    float* s_ws  = sm + OFF_R;    // wsQ[128][32] (quarter of ws1T, s1-scaled)
    float* s_Mq  = sm + OFF_R;    // MQ[32][132] (quarter of M, overlays wsQ)
    float* s_s1  = sm + OFF_S1;
    float* s_h1  = sm + OFF_H1;   // h1 -> e1
    float* s_g2  = sm + OFF_G2;   // g2 -> jac partials
    float* s_d2  = sm + OFF_D2;
    float* s_u   = sm + OFF_U;
    float* s_x   = sm + OFF_X;
    float* s_jac = sm + OFF_JAC;
    float* s_T1  = sm + OFF_T1;
    float* s_T2  = sm + OFF_T2;
    float* s_aug = sm + OFF_AUG;

    // ---- P0: x row; qd half of output ----
    if (t < 32) s_x[t] = x[b*32 + t];
    if (t < 16) out[b*32 + t] = x[b*32 + 16 + t];
    __syncthreads();

    // ---- P1: z1 -> s1, h1 (coalesced W1 row reads) ----
    #pragma unroll
    for (int rep = 0; rep < 2; ++rep) {
        const int j = t + rep*256;
        float z = b1[j];
        #pragma unroll
        for (int i = 0; i < 32; ++i) z = fmaf(s_x[i], W1[i*512 + j], z);
        const float e = expf(-fabsf(z));
        const float s = (z >= 0.f) ? 1.f/(1.f+e) : e/(1.f+e);
        s_s1[j] = s;
        s_h1[j] = fmaxf(z, 0.f) + log1pf(e);
    }

    // ---- P2: GEMM M = ws1 @ W2, quarter-staged A (col-split: wave w -> cols
    //          w*128..; lane: 4 rgrp x 16 cgrp); fused z2 accumulation ----
    const int r0 = (lane >> 4) * 8;
    const int c0 = w*128 + (lane & 15) * 8;

    float acc[8][8];
    #pragma unroll
    for (int ii = 0; ii < 8; ++ii)
        #pragma unroll
        for (int kk = 0; kk < 8; ++kk) acc[ii][kk] = 0.f;

    float zacc[8];
    {
        const float4 bz0 = *(const float4*)(b2 + c0);
        const float4 bz1 = *(const float4*)(b2 + c0 + 4);
        zacc[0]=bz0.x; zacc[1]=bz0.y; zacc[2]=bz0.z; zacc[3]=bz0.w;
        zacc[4]=bz1.x; zacc[5]=bz1.y; zacc[6]=bz1.z; zacc[7]=bz1.w;
    }

    const float4* W2v4  = (const float4*)W2;
    const float4* W1Tv4 = (const float4*)W1T;
    const int cq = c0 >> 2;

    for (int q = 0; q < 4; ++q) {
        __syncthreads();   // q=0: covers P1 s1/h1 writes; q>0: wsQ reads done
        // restage wsQ = W1T[quarter] * s1  (coalesced f4 loads, conflict-free stores)
        #pragma unroll
        for (int r = 0; r < 4; ++r) {
            const int f = r*256 + t;               // f4 index within quarter
            float4 v = W1Tv4[q*1024 + f];
            const float s = s_s1[q*128 + (f >> 3)];
            v.x*=s; v.y*=s; v.z*=s; v.w*=s;
            ((float4*)s_ws)[f] = v;
        }
        __syncthreads();

        #pragma unroll 2
        for (int jj = 0; jj < 128; ++jj) {
            const int j = q*128 + jj;
            const float4 bb0 = W2v4[j*128 + cq];
            const float4 bb1 = W2v4[j*128 + cq + 1];
            const float4 a0 = *(const float4*)(s_ws + jj*32 + r0);
            const float4 a1 = *(const float4*)(s_ws + jj*32 + r0 + 4);
            const float h1j = s_h1[j];
            const float av[8] = {a0.x,a0.y,a0.z,a0.w,a1.x,a1.y,a1.z,a1.w};
            const float bv[8] = {bb0.x,bb0.y,bb0.z,bb0.w,bb1.x,bb1.y,bb1.z,bb1.w};
            #pragma unroll
            for (int ii = 0; ii < 8; ++ii)
                #pragma unroll
                for (int kk = 0; kk < 8; ++kk)
                    acc[ii][kk] = fmaf(av[ii], bv[kk], acc[ii][kk]);
            #pragma unroll
            for (int kk = 0; kk < 8; ++kk)
                zacc[kk] = fmaf(h1j, bv[kk], zacc[kk]);
        }
    }

    // z2 -> g2, d2 for own 8 cols
    {
        const float4 w30 = *(const float4*)(W3 + c0);
        const float4 w31 = *(const float4*)(W3 + c0 + 4);
        const float w3v[8] = {w30.x,w30.y,w30.z,w30.w,w31.x,w31.y,w31.z,w31.w};
        #pragma unroll
        for (int kk = 0; kk < 8; ++kk) {
            const float z = zacc[kk];
            const float e = expf(-fabsf(z));
            const float sg = (z >= 0.f) ? 1.f/(1.f+e) : e/(1.f+e);
            s_g2[c0+kk] = w3v[kk] * sg;
            s_d2[c0+kk] = w3v[kk] * sg * (1.f - sg);
        }
    }
    __syncthreads();

    // ---- P3: u[j] = W2[j,:] . g2 (wave w -> j in [w*128, w*128+128)),
    //          2-way ILP on the shuffle-reduce chains ----
    {
        float g2f[8];
        {
            const float4 ga = *(const float4*)(s_g2 + lane*8);
            const float4 gb = *(const float4*)(s_g2 + lane*8 + 4);
            g2f[0]=ga.x; g2f[1]=ga.y; g2f[2]=ga.z; g2f[3]=ga.w;
            g2f[4]=gb.x; g2f[5]=gb.y; g2f[6]=gb.z; g2f[7]=gb.w;
        }
        for (int jj = 0; jj < 64; ++jj) {
            const int j0 = w*128 + jj;
            const int j1 = j0 + 64;
            const float4 ra0 = *(const float4*)(W2 + j0*512 + lane*8);
            const float4 rb0 = *(const float4*)(W2 + j0*512 + lane*8 + 4);
            const float4 ra1 = *(const float4*)(W2 + j1*512 + lane*8);
            const float4 rb1 = *(const float4*)(W2 + j1*512 + lane*8 + 4);
            float p0 = ra0.x*g2f[0];
            p0 = fmaf(ra0.y, g2f[1], p0); p0 = fmaf(ra0.z, g2f[2], p0); p0 = fmaf(ra0.w, g2f[3], p0);
            p0 = fmaf(rb0.x, g2f[4], p0); p0 = fmaf(rb0.y, g2f[5], p0);
            p0 = fmaf(rb0.z, g2f[6], p0); p0 = fmaf(rb0.w, g2f[7], p0);
            float p1 = ra1.x*g2f[0];
            p1 = fmaf(ra1.y, g2f[1], p1); p1 = fmaf(ra1.z, g2f[2], p1); p1 = fmaf(ra1.w, g2f[3], p1);
            p1 = fmaf(rb1.x, g2f[4], p1); p1 = fmaf(rb1.y, g2f[5], p1);
            p1 = fmaf(rb1.z, g2f[6], p1); p1 = fmaf(rb1.w, g2f[7], p1);
            #pragma unroll
            for (int off = 32; off >= 1; off >>= 1) {
                p0 += __shfl_xor(p0, off);
                p1 += __shfl_xor(p1, off);
            }
            if (lane == 0) { s_u[j0] = p0; s_u[j1] = p1; }
        }
    }
    __syncthreads();

    // ---- P4e: e1 = u(1-s1)/s1 into s_h1 (h1 dead) ----
    #pragma unroll
    for (int rep = 0; rep < 2; ++rep) {
        const int j = t + rep*256;
        const float uj = s_u[j], s = s_s1[j];
        s_h1[j] = uj * (1.f - s) / s;
    }

    // ---- P4/P5 quarter-staged: jac partials + term1 ----
    const int i5 = 16 + (t >> 4);
    const int c5 = 2 * (t & 15);
    float jacp = 0.f, t1a = 0.f, t1b = 0.f;

    for (int q = 0; q < 4; ++q) {
        __syncthreads();   // q=0: e1 writes visible; q>0: wsQ reads done
        #pragma unroll
        for (int r = 0; r < 4; ++r) {
            const int f = r*256 + t;
            float4 v = W1Tv4[q*1024 + f];
            const float s = s_s1[q*128 + (f >> 3)];
            v.x*=s; v.y*=s; v.z*=s; v.w*=s;
            ((float4*)s_ws)[f] = v;
        }
        __syncthreads();

        // P4 partial: quarter q's segs (4q..4q+3) live entirely in wave q
        if (w == q) {
            const int i  = t & 15;
            const int jb = (lane >> 4) * 32;       // local j base
            #pragma unroll 8
            for (int jj = 0; jj < 32; ++jj)
                jacp = fmaf(s_ws[(jb+jj)*32 + i], s_u[q*128 + jb + jj], jacp);
        }

        // P5 partial: term1 over this quarter (all threads)
        #pragma unroll 4
        for (int jj = 0; jj < 128; ++jj) {
            const float e   = s_h1[q*128 + jj];
            const float wsi = s_ws[jj*32 + i5];
            const float tt  = wsi * e;
            t1a = fmaf(tt, s_ws[jj*32 + c5],     t1a);
            t1b = fmaf(tt, s_ws[jj*32 + c5 + 1], t1b);
        }
    }
    s_T1[(i5-16)*33 + c5]     = t1a;
    s_T1[(i5-16)*33 + c5 + 1] = t1b;
    s_g2[(t>>4)*16 + (t&15)]  = jacp;   // g2 dead after P3; reuse for jac partials
    __syncthreads();

    // fold jac
    if (t < 16) {
        float p = 0.f;
        #pragma unroll
        for (int seg = 0; seg < 16; ++seg) p += s_g2[seg*16 + t];
        s_jac[t] = p;
    }

    // ---- P6/P7 quarter-passed: term2 = M D2 M^T (rows 16..31 x cols 0..31) ----
    {
        float h0 = 0.f, h1v = 0.f;
        const float4* d2v = (const float4*)s_d2;
        for (int p = 0; p < 4; ++p) {
            if (w == p) {   // wave p owns cols [p*128, p*128+128) in registers
                #pragma unroll
                for (int ii = 0; ii < 8; ++ii) {
                    float* rp = s_Mq + (r0+ii)*MQS + (lane & 15)*8;
                    *(float4*)(rp)     = make_float4(acc[ii][0],acc[ii][1],acc[ii][2],acc[ii][3]);
                    *(float4*)(rp + 4) = make_float4(acc[ii][4],acc[ii][5],acc[ii][6],acc[ii][7]);
                }
            }
            __syncthreads();
            const float4* Mi = (const float4*)(s_Mq + i5*MQS);
            const float4* Ma = (const float4*)(s_Mq + c5*MQS);
            const float4* Mb = (const float4*)(s_Mq + (c5+1)*MQS);
            for (int qq = 0; qq < 32; ++qq) {
                const float4 d  = d2v[p*32 + qq];
                const float4 mi = Mi[qq];
                const float4 ma = Ma[qq];
                const float4 mb = Mb[qq];
                float tt;
                tt = mi.x*d.x; h0 = fmaf(tt, ma.x, h0); h1v = fmaf(tt, mb.x, h1v);
                tt = mi.y*d.y; h0 = fmaf(tt, ma.y, h0); h1v = fmaf(tt, mb.y, h1v);
                tt = mi.z*d.z; h0 = fmaf(tt, ma.z, h0); h1v = fmaf(tt, mb.z, h1v);
                tt = mi.w*d.w; h0 = fmaf(tt, ma.w, h0); h1v = fmaf(tt, mb.w, h1v);
            }
            __syncthreads();   // reads done before next pass overwrites MQ
        }
        s_T2[(i5-16)*33 + c5]     = h0;
        s_T2[(i5-16)*33 + c5 + 1] = h1v;
    }
    __syncthreads();

    // ---- P8: aug = [A | rhs] ----
    {
        const int r = t >> 4, c = t & 15;
        s_aug[r*17 + c] = s_T1[r*33 + 16 + c] + s_T2[r*33 + 16 + c];
    }
    if (t < 16) {
        float p = s_jac[t];
        #pragma unroll
        for (int c = 0; c < 16; ++c)
            p -= (s_T1[t*33 + c] + s_T2[t*33 + c]) * s_x[16 + c];
        s_aug[t*17 + 16] = p;
    }
    __syncthreads();

    // ---- P9: single-wave fp64 Jacobi pinv solve (no block barriers) ----
    if (w != 0) return;

    double* Ad  = (double*)sm;       // [16][17] (overlays region R)
    double* Vd  = Ad + 272;          // [16][17]
    double* c8  = Vd + 272;          // [8]
    double* sn8 = c8 + 8;            // [8]
    double* il  = sn8 + 8;           // [16]
    double* yv  = il + 16;           // [16]

    for (int idx = t; idx < 272; idx += 64) {
        const int r = idx / 17, c = idx - r*17;
        double a = 0.0;
        if (c < 16) a = 0.5 * ((double)s_aug[r*17 + c] + (double)s_aug[c*17 + r]);
        Ad[idx] = a;
        Vd[idx] = (c < 16 && r == c) ? 1.0 : 0.0;
    }
    wave_fence();

    for (int sweep = 0; sweep < NSWEEP; ++sweep) {
        for (int rr = 0; rr < 15; ++rr) {
            if (t < 8) {
                int p, q; pairpq(rr, t, p, q);
                const double app = Ad[p*17 + p], aqq = Ad[q*17 + q], apq = Ad[p*17 + q];
                double cc = 1.0, ss = 0.0;
                if (apq != 0.0) {
                    const double tau = (aqq - app) / (2.0 * apq);
                    const double tt = ((tau >= 0.0) ? 1.0 : -1.0) / (fabs(tau) + sqrt(1.0 + tau*tau));
                    cc = 1.0 / sqrt(1.0 + tt*tt);
                    ss = tt * cc;
                }
                c8[t] = cc; sn8[t] = ss;
            }
            wave_fence();
            #pragma unroll
            for (int k = 0; k < 2; ++k) {      // rows: A <- J^T A (128 items)
                const int id = t + 64*k;
                const int m = id >> 4, j = id & 15;
                int p, q; pairpq(rr, m, p, q);
                const double cc = c8[m], ss = sn8[m];
                const double ap = Ad[p*17 + j], aq = Ad[q*17 + j];
                Ad[p*17 + j] = cc*ap - ss*aq;
                Ad[q*17 + j] = ss*ap + cc*aq;
            }
            #pragma unroll
            for (int k = 0; k < 2; ++k) {      // V <- V J (128 items, disjoint array)
                const int id = t + 64*k;
                const int m = id >> 4, i = id & 15;
                int p, q; pairpq(rr, m, p, q);
                const double cc = c8[m], ss = sn8[m];
                const double vp = Vd[i*17 + p], vq = Vd[i*17 + q];
                Vd[i*17 + p] = cc*vp - ss*vq;
                Vd[i*17 + q] = ss*vp + cc*vq;
            }
            wave_fence();
            #pragma unroll
            for (int k = 0; k < 2; ++k) {      // cols: A <- A J (128 items)
                const int id = t + 64*k;
                const int m = id >> 4, i = id & 15;
                int p, q; pairpq(rr, m, p, q);
                const double cc = c8[m], ss = sn8[m];
                const double ap = Ad[i*17 + p], aq = Ad[i*17 + q];
                Ad[i*17 + p] = cc*ap - ss*aq;
                Ad[i*17 + q] = ss*ap + cc*aq;
            }
            wave_fence();
        }
    }

    if (t == 0) {
        double mx = 0.0;
        #pragma unroll
        for (int i = 0; i < 16; ++i) mx = fmax(mx, fabs(Ad[i*17 + i]));
        const double cut = JAX_RCOND * mx;
        #pragma unroll
        for (int i = 0; i < 16; ++i) {
            const double l = Ad[i*17 + i];
            il[i] = (fabs(l) > cut) ? (1.0 / l) : 0.0;
        }
    }
    wave_fence();

    if (t < 16) {
        double a = 0.0;
        #pragma unroll
        for (int r = 0; r < 16; ++r) a += Vd[r*17 + t] * (double)s_aug[r*17 + 16];
        yv[t] = a;
    }
    wave_fence();

    if (t < 16) {
        double a = 0.0;
        #pragma unroll
        for (int i = 0; i < 16; ++i) a += Vd[t*17 + i] * (il[i] * yv[i]);
        out[b*32 + 16 + t] = (float)a;
    }
}

extern "C" void kernel_launch(void* const* d_in, const int* in_sizes, int n_in,
                              void* d_out, int out_size, void* d_ws, size_t ws_size,
                              hipStream_t stream) {
    const float* x  = (const float*)d_in[0];
    const float* W1 = (const float*)d_in[1];
    const float* b1 = (const float*)d_in[2];
    const float* W2 = (const float*)d_in[3];
    const float* b2 = (const float*)d_in[4];
    const float* W3 = (const float*)d_in[5];
    float* out = (float*)d_out;
    float* W1T = (float*)d_ws;    // 64 KB scratch
    const int bs = in_sizes[0] / 32;

    hipFuncSetAttribute((const void*)lnn_kernel,
                        hipFuncAttributeMaxDynamicSharedMemorySize, SMEM_BYTES);
    w1_transpose<<<dim3(64), dim3(256), 0, stream>>>(W1, W1T);
    lnn_kernel<<<dim3(bs), dim3(256), SMEM_BYTES, stream>>>(x, W1, W1T, b1, W2, b2, W3, out);
}

// Round 3
// 4833.675 us; speedup vs baseline: 1.5137x; 1.1265x over previous
//
#include <hip/hip_runtime.h>
#include <math.h>

// LNN: BS=16384, d=32 (n=16), HID=512. All fp32.
// H = W1 D1 W1^T + M D2 M^T,  M = (W1^T diag(s1)) W2,  jac = W1 (s1*u),
// u = W2 (W3*s2), e1 = u(1-s1)/s1 so term1 = ws1T^T diag(e1) ws1T.
// out[:, :16] = qd = x[:,16:]; out[:,16:] = pinv(A) rhs  (fp64 Jacobi eig, JAX rcond).
//
// R2: kernel split — lnn_main (P0-P8) writes aug[272]/sample to d_ws; lnn_solve
// runs the identical fp64 Jacobi one-wave-per-sample at 8 blocks/CU so the
// LDS-latency-serial rotation chains are TLP-hidden.
// R3 fix: the aug store used `if (t<272)` with blockDim=256 — elements 256..271
// (row 15 of A, rhs[15]) were never stored; solve consumed poisoned workspace.
// Store the 16-element tail with threads 0..15. No other change.

#define NSWEEP 5
#define JAX_RCOND 1.9073486e-5   // 10 * 16 * eps_f32

#define MQS 132                   // M quarter row stride (floats), 33 float4s

// LDS float offsets (main)
#define OFF_R    0                 // wsQ[128][32] / MQ[32][132] / (fallback) fp64 ws
#define R_FLOATS 4224
#define OFF_S1   (OFF_R + R_FLOATS)
#define OFF_H1   (OFF_S1+512)      // h1, later e1
#define OFF_G2   (OFF_H1+512)      // g2, later jac partials [16][16]
#define OFF_D2   (OFF_G2+512)
#define OFF_U    (OFF_D2+512)
#define OFF_X    (OFF_U+512)
#define OFF_JAC  (OFF_X+32)
#define OFF_T1   (OFF_JAC+16)      // [16][33]
#define OFF_T2   (OFF_T1+528)      // [16][33]
#define OFF_AUG  (OFF_T2+528)      // [16][17]
#define SMEM_FLOATS (OFF_AUG+272)
#define SMEM_BYTES  (SMEM_FLOATS*4)   // 32640 B -> 4 blocks/CU (reg-capped at 128/thread)

// solve kernel: 592 doubles per wave, 4 waves/block
#define SOLVE_WAVE_DBL 592
#define SOLVE_SMEM_BYTES (4*SOLVE_WAVE_DBL*8)   // 18944 B -> 8 blocks/CU

__device__ __forceinline__ void pairpq(int r, int m, int& p, int& q) {
    p = (m == 0) ? 0 : 1 + (m - 1 + r) % 15;
    q = 1 + (14 - m + r) % 15;
}

__device__ __forceinline__ void wave_fence() {
    __builtin_amdgcn_wave_barrier();
    __builtin_amdgcn_s_waitcnt(0);     // drain vm/exp/lgkm; DS ops of a wave retire in order
    __builtin_amdgcn_wave_barrier();
}

// Shared fp64 Jacobi pinv solve: one wave, lane-indexed, private LDS region.
// Arithmetic and order IDENTICAL to the original in-kernel P9.
// gaug: 272 fp32 [16][17] augmented [A|rhs]; writes qdd to outp[0..15].
__device__ __forceinline__ void jacobi_solve_wave(
    const float* __restrict__ gaug, double* __restrict__ ws,
    float* __restrict__ outp, int lane)
{
    double* Ad  = ws;                // [16][17]
    double* Vd  = Ad + 272;          // [16][17]
    double* c8  = Vd + 272;          // [8]
    double* sn8 = c8 + 8;            // [8]
    double* il  = sn8 + 8;           // [16]
    double* yv  = il + 16;           // [16]

    for (int idx = lane; idx < 272; idx += 64) {
        const int r = idx / 17, c = idx - r*17;
        double a = 0.0;
        if (c < 16) a = 0.5 * ((double)gaug[r*17 + c] + (double)gaug[c*17 + r]);
        Ad[idx] = a;
        Vd[idx] = (c < 16 && r == c) ? 1.0 : 0.0;
    }
    wave_fence();

    for (int sweep = 0; sweep < NSWEEP; ++sweep) {
        for (int rr = 0; rr < 15; ++rr) {
            if (lane < 8) {
                int p, q; pairpq(rr, lane, p, q);
                const double app = Ad[p*17 + p], aqq = Ad[q*17 + q], apq = Ad[p*17 + q];
                double cc = 1.0, ss = 0.0;
                if (apq != 0.0) {
                    const double tau = (aqq - app) / (2.0 * apq);
                    const double tt = ((tau >= 0.0) ? 1.0 : -1.0) / (fabs(tau) + sqrt(1.0 + tau*tau));
                    cc = 1.0 / sqrt(1.0 + tt*tt);
                    ss = tt * cc;
                }
                c8[lane] = cc; sn8[lane] = ss;
            }
            wave_fence();
            #pragma unroll
            for (int k = 0; k < 2; ++k) {      // rows: A <- J^T A (128 items)
                const int id = lane + 64*k;
                const int m = id >> 4, j = id & 15;
                int p, q; pairpq(rr, m, p, q);
                const double cc = c8[m], ss = sn8[m];
                const double ap = Ad[p*17 + j], aq = Ad[q*17 + j];
                Ad[p*17 + j] = cc*ap - ss*aq;
                Ad[q*17 + j] = ss*ap + cc*aq;
            }
            #pragma unroll
            for (int k = 0; k < 2; ++k) {      // V <- V J (128 items, disjoint array)
                const int id = lane + 64*k;
                const int m = id >> 4, i = id & 15;
                int p, q; pairpq(rr, m, p, q);
                const double cc = c8[m], ss = sn8[m];
                const double vp = Vd[i*17 + p], vq = Vd[i*17 + q];
                Vd[i*17 + p] = cc*vp - ss*vq;
                Vd[i*17 + q] = ss*vp + cc*vq;
            }
            wave_fence();
            #pragma unroll
            for (int k = 0; k < 2; ++k) {      // cols: A <- A J (128 items)
                const int id = lane + 64*k;
                const int m = id >> 4, i = id & 15;
                int p, q; pairpq(rr, m, p, q);
                const double cc = c8[m], ss = sn8[m];
                const double ap = Ad[i*17 + p], aq = Ad[i*17 + q];
                Ad[i*17 + p] = cc*ap - ss*aq;
                Ad[i*17 + q] = ss*ap + cc*aq;
            }
            wave_fence();
        }
    }

    if (lane == 0) {
        double mx = 0.0;
        #pragma unroll
        for (int i = 0; i < 16; ++i) mx = fmax(mx, fabs(Ad[i*17 + i]));
        const double cut = JAX_RCOND * mx;
        #pragma unroll
        for (int i = 0; i < 16; ++i) {
            const double l = Ad[i*17 + i];
            il[i] = (fabs(l) > cut) ? (1.0 / l) : 0.0;
        }
    }
    wave_fence();

    if (lane < 16) {
        double a = 0.0;
        #pragma unroll
        for (int r = 0; r < 16; ++r) a += Vd[r*17 + lane] * (double)gaug[r*17 + 16];
        yv[lane] = a;
    }
    wave_fence();

    if (lane < 16) {
        double a = 0.0;
        #pragma unroll
        for (int i = 0; i < 16; ++i) a += Vd[lane*17 + i] * (il[i] * yv[i]);
        outp[lane] = (float)a;
    }
}

// Pre-kernel: W1T[j*32+i] = W1[i*512+j]   (64 KB, L2-resident afterwards)
extern "C" __global__ void w1_transpose(const float* __restrict__ W1,
                                        float* __restrict__ W1T) {
    const int t = blockIdx.x * 256 + threadIdx.x;   // t = j*32 + i
    W1T[t] = W1[(t & 31) * 512 + (t >> 5)];
}

extern "C" __global__ __launch_bounds__(256, 4)
void lnn_kernel(const float* __restrict__ x,
                const float* __restrict__ W1,
                const float* __restrict__ W1T,
                const float* __restrict__ b1,
                const float* __restrict__ W2, const float* __restrict__ b2,
                const float* __restrict__ W3,
                float* __restrict__ out,
                float* __restrict__ aug_g,
                const int solveInMain)
{
    const int b = blockIdx.x;
    const int t = threadIdx.x;
    const int lane = t & 63;
    const int w = t >> 6;

    extern __shared__ float sm[];
    float* s_ws  = sm + OFF_R;    // wsQ[128][32] (quarter of ws1T, s1-scaled)
    float* s_Mq  = sm + OFF_R;    // MQ[32][132] (quarter of M, overlays wsQ)
    float* s_s1  = sm + OFF_S1;
    float* s_h1  = sm + OFF_H1;   // h1 -> e1
    float* s_g2  = sm + OFF_G2;   // g2 -> jac partials
    float* s_d2  = sm + OFF_D2;
    float* s_u   = sm + OFF_U;
    float* s_x   = sm + OFF_X;
    float* s_jac = sm + OFF_JAC;
    float* s_T1  = sm + OFF_T1;
    float* s_T2  = sm + OFF_T2;
    float* s_aug = sm + OFF_AUG;

    // ---- P0: x row; qd half of output ----
    if (t < 32) s_x[t] = x[b*32 + t];
    if (t < 16) out[b*32 + t] = x[b*32 + 16 + t];
    __syncthreads();

    // ---- P1: z1 -> s1, h1 (coalesced W1 row reads) ----
    #pragma unroll
    for (int rep = 0; rep < 2; ++rep) {
        const int j = t + rep*256;
        float z = b1[j];
        #pragma unroll
        for (int i = 0; i < 32; ++i) z = fmaf(s_x[i], W1[i*512 + j], z);
        const float e = expf(-fabsf(z));
        const float s = (z >= 0.f) ? 1.f/(1.f+e) : e/(1.f+e);
        s_s1[j] = s;
        s_h1[j] = fmaxf(z, 0.f) + log1pf(e);
    }

    // ---- P2: GEMM M = ws1 @ W2, quarter-staged A (col-split: wave w -> cols
    //          w*128..; lane: 4 rgrp x 16 cgrp); fused z2 accumulation ----
    const int r0 = (lane >> 4) * 8;
    const int c0 = w*128 + (lane & 15) * 8;

    float acc[8][8];
    #pragma unroll
    for (int ii = 0; ii < 8; ++ii)
        #pragma unroll
        for (int kk = 0; kk < 8; ++kk) acc[ii][kk] = 0.f;

    float zacc[8];
    {
        const float4 bz0 = *(const float4*)(b2 + c0);
        const float4 bz1 = *(const float4*)(b2 + c0 + 4);
        zacc[0]=bz0.x; zacc[1]=bz0.y; zacc[2]=bz0.z; zacc[3]=bz0.w;
        zacc[4]=bz1.x; zacc[5]=bz1.y; zacc[6]=bz1.z; zacc[7]=bz1.w;
    }

    const float4* W2v4  = (const float4*)W2;
    const float4* W1Tv4 = (const float4*)W1T;
    const int cq = c0 >> 2;

    for (int q = 0; q < 4; ++q) {
        __syncthreads();   // q=0: covers P1 s1/h1 writes; q>0: wsQ reads done
        // restage wsQ = W1T[quarter] * s1  (coalesced f4 loads, conflict-free stores)
        #pragma unroll
        for (int r = 0; r < 4; ++r) {
            const int f = r*256 + t;               // f4 index within quarter
            float4 v = W1Tv4[q*1024 + f];
            const float s = s_s1[q*128 + (f >> 3)];
            v.x*=s; v.y*=s; v.z*=s; v.w*=s;
            ((float4*)s_ws)[f] = v;
        }
        __syncthreads();

        #pragma unroll 2
        for (int jj = 0; jj < 128; ++jj) {
            const int j = q*128 + jj;
            const float4 bb0 = W2v4[j*128 + cq];
            const float4 bb1 = W2v4[j*128 + cq + 1];
            const float4 a0 = *(const float4*)(s_ws + jj*32 + r0);
            const float4 a1 = *(const float4*)(s_ws + jj*32 + r0 + 4);
            const float h1j = s_h1[j];
            const float av[8] = {a0.x,a0.y,a0.z,a0.w,a1.x,a1.y,a1.z,a1.w};
            const float bv[8] = {bb0.x,bb0.y,bb0.z,bb0.w,bb1.x,bb1.y,bb1.z,bb1.w};
            #pragma unroll
            for (int ii = 0; ii < 8; ++ii)
                #pragma unroll
                for (int kk = 0; kk < 8; ++kk)
                    acc[ii][kk] = fmaf(av[ii], bv[kk], acc[ii][kk]);
            #pragma unroll
            for (int kk = 0; kk < 8; ++kk)
                zacc[kk] = fmaf(h1j, bv[kk], zacc[kk]);
        }
    }

    // z2 -> g2, d2 for own 8 cols
    {
        const float4 w30 = *(const float4*)(W3 + c0);
        const float4 w31 = *(const float4*)(W3 + c0 + 4);
        const float w3v[8] = {w30.x,w30.y,w30.z,w30.w,w31.x,w31.y,w31.z,w31.w};
        #pragma unroll
        for (int kk = 0; kk < 8; ++kk) {
            const float z = zacc[kk];
            const float e = expf(-fabsf(z));
            const float sg = (z >= 0.f) ? 1.f/(1.f+e) : e/(1.f+e);
            s_g2[c0+kk] = w3v[kk] * sg;
            s_d2[c0+kk] = w3v[kk] * sg * (1.f - sg);
        }
    }
    __syncthreads();

    // ---- P3: u[j] = W2[j,:] . g2 (wave w -> j in [w*128, w*128+128)),
    //          2-way ILP on the shuffle-reduce chains ----
    {
        float g2f[8];
        {
            const float4 ga = *(const float4*)(s_g2 + lane*8);
            const float4 gb = *(const float4*)(s_g2 + lane*8 + 4);
            g2f[0]=ga.x; g2f[1]=ga.y; g2f[2]=ga.z; g2f[3]=ga.w;
            g2f[4]=gb.x; g2f[5]=gb.y; g2f[6]=gb.z; g2f[7]=gb.w;
        }
        for (int jj = 0; jj < 64; ++jj) {
            const int j0 = w*128 + jj;
            const int j1 = j0 + 64;
            const float4 ra0 = *(const float4*)(W2 + j0*512 + lane*8);
            const float4 rb0 = *(const float4*)(W2 + j0*512 + lane*8 + 4);
            const float4 ra1 = *(const float4*)(W2 + j1*512 + lane*8);
            const float4 rb1 = *(const float4*)(W2 + j1*512 + lane*8 + 4);
            float p0 = ra0.x*g2f[0];
            p0 = fmaf(ra0.y, g2f[1], p0); p0 = fmaf(ra0.z, g2f[2], p0); p0 = fmaf(ra0.w, g2f[3], p0);
            p0 = fmaf(rb0.x, g2f[4], p0); p0 = fmaf(rb0.y, g2f[5], p0);
            p0 = fmaf(rb0.z, g2f[6], p0); p0 = fmaf(rb0.w, g2f[7], p0);
            float p1 = ra1.x*g2f[0];
            p1 = fmaf(ra1.y, g2f[1], p1); p1 = fmaf(ra1.z, g2f[2], p1); p1 = fmaf(ra1.w, g2f[3], p1);
            p1 = fmaf(rb1.x, g2f[4], p1); p1 = fmaf(rb1.y, g2f[5], p1);
            p1 = fmaf(rb1.z, g2f[6], p1); p1 = fmaf(rb1.w, g2f[7], p1);
            #pragma unroll
            for (int off = 32; off >= 1; off >>= 1) {
                p0 += __shfl_xor(p0, off);
                p1 += __shfl_xor(p1, off);
            }
            if (lane == 0) { s_u[j0] = p0; s_u[j1] = p1; }
        }
    }
    __syncthreads();

    // ---- P4e: e1 = u(1-s1)/s1 into s_h1 (h1 dead) ----
    #pragma unroll
    for (int rep = 0; rep < 2; ++rep) {
        const int j = t + rep*256;
        const float uj = s_u[j], s = s_s1[j];
        s_h1[j] = uj * (1.f - s) / s;
    }

    // ---- P4/P5 quarter-staged: jac partials + term1 ----
    const int i5 = 16 + (t >> 4);
    const int c5 = 2 * (t & 15);
    float jacp = 0.f, t1a = 0.f, t1b = 0.f;

    for (int q = 0; q < 4; ++q) {
        __syncthreads();   // q=0: e1 writes visible; q>0: wsQ reads done
        #pragma unroll
        for (int r = 0; r < 4; ++r) {
            const int f = r*256 + t;
            float4 v = W1Tv4[q*1024 + f];
            const float s = s_s1[q*128 + (f >> 3)];
            v.x*=s; v.y*=s; v.z*=s; v.w*=s;
            ((float4*)s_ws)[f] = v;
        }
        __syncthreads();

        // P4 partial: quarter q's segs (4q..4q+3) live entirely in wave q
        if (w == q) {
            const int i  = t & 15;
            const int jb = (lane >> 4) * 32;       // local j base
            #pragma unroll 8
            for (int jj = 0; jj < 32; ++jj)
                jacp = fmaf(s_ws[(jb+jj)*32 + i], s_u[q*128 + jb + jj], jacp);
        }

        // P5 partial: term1 over this quarter (all threads)
        #pragma unroll 4
        for (int jj = 0; jj < 128; ++jj) {
            const float e   = s_h1[q*128 + jj];
            const float wsi = s_ws[jj*32 + i5];
            const float tt  = wsi * e;
            t1a = fmaf(tt, s_ws[jj*32 + c5],     t1a);
            t1b = fmaf(tt, s_ws[jj*32 + c5 + 1], t1b);
        }
    }
    s_T1[(i5-16)*33 + c5]     = t1a;
    s_T1[(i5-16)*33 + c5 + 1] = t1b;
    s_g2[(t>>4)*16 + (t&15)]  = jacp;   // g2 dead after P3; reuse for jac partials
    __syncthreads();

    // fold jac
    if (t < 16) {
        float p = 0.f;
        #pragma unroll
        for (int seg = 0; seg < 16; ++seg) p += s_g2[seg*16 + t];
        s_jac[t] = p;
    }

    // ---- P6/P7 quarter-passed: term2 = M D2 M^T (rows 16..31 x cols 0..31) ----
    {
        float h0 = 0.f, h1v = 0.f;
        const float4* d2v = (const float4*)s_d2;
        for (int p = 0; p < 4; ++p) {
            if (w == p) {   // wave p owns cols [p*128, p*128+128) in registers
                #pragma unroll
                for (int ii = 0; ii < 8; ++ii) {
                    float* rp = s_Mq + (r0+ii)*MQS + (lane & 15)*8;
                    *(float4*)(rp)     = make_float4(acc[ii][0],acc[ii][1],acc[ii][2],acc[ii][3]);
                    *(float4*)(rp + 4) = make_float4(acc[ii][4],acc[ii][5],acc[ii][6],acc[ii][7]);
                }
            }
            __syncthreads();
            const float4* Mi = (const float4*)(s_Mq + i5*MQS);
            const float4* Ma = (const float4*)(s_Mq + c5*MQS);
            const float4* Mb = (const float4*)(s_Mq + (c5+1)*MQS);
            for (int qq = 0; qq < 32; ++qq) {
                const float4 d  = d2v[p*32 + qq];
                const float4 mi = Mi[qq];
                const float4 ma = Ma[qq];
                const float4 mb = Mb[qq];
                float tt;
                tt = mi.x*d.x; h0 = fmaf(tt, ma.x, h0); h1v = fmaf(tt, mb.x, h1v);
                tt = mi.y*d.y; h0 = fmaf(tt, ma.y, h0); h1v = fmaf(tt, mb.y, h1v);
                tt = mi.z*d.z; h0 = fmaf(tt, ma.z, h0); h1v = fmaf(tt, mb.z, h1v);
                tt = mi.w*d.w; h0 = fmaf(tt, ma.w, h0); h1v = fmaf(tt, mb.w, h1v);
            }
            __syncthreads();   // reads done before next pass overwrites MQ
        }
        s_T2[(i5-16)*33 + c5]     = h0;
        s_T2[(i5-16)*33 + c5 + 1] = h1v;
    }
    __syncthreads();

    // ---- P8: aug = [A | rhs] ----
    {
        const int r = t >> 4, c = t & 15;
        s_aug[r*17 + c] = s_T1[r*33 + 16 + c] + s_T2[r*33 + 16 + c];
    }
    if (t < 16) {
        float p = s_jac[t];
        #pragma unroll
        for (int c = 0; c < 16; ++c)
            p -= (s_T1[t*33 + c] + s_T2[t*33 + c]) * s_x[16 + c];
        s_aug[t*17 + 16] = p;
    }
    __syncthreads();

    if (!solveInMain) {
        // ---- P8b: store aug (272 floats with 256 threads: body + 16-elem tail) ----
        aug_g[b*272 + t] = s_aug[t];
        if (t < 16) aug_g[b*272 + 256 + t] = s_aug[256 + t];
        return;
    }

    // ---- Fallback P9: single-wave fp64 Jacobi (only if workspace too small) ----
    if (w != 0) return;
    jacobi_solve_wave(s_aug, (double*)sm, out + b*32 + 16, lane);
}

extern "C" __global__ __launch_bounds__(256, 8)
void lnn_solve(const float* __restrict__ aug_g, float* __restrict__ out)
{
    const int t = threadIdx.x;
    const int lane = t & 63;
    const int w = t >> 6;
    const int b = blockIdx.x * 4 + w;

    extern __shared__ double dsm[];
    jacobi_solve_wave(aug_g + b*272, dsm + w*SOLVE_WAVE_DBL, out + b*32 + 16, lane);
}

extern "C" void kernel_launch(void* const* d_in, const int* in_sizes, int n_in,
                              void* d_out, int out_size, void* d_ws, size_t ws_size,
                              hipStream_t stream) {
    const float* x  = (const float*)d_in[0];
    const float* W1 = (const float*)d_in[1];
    const float* b1 = (const float*)d_in[2];
    const float* W2 = (const float*)d_in[3];
    const float* b2 = (const float*)d_in[4];
    const float* W3 = (const float*)d_in[5];
    float* out = (float*)d_out;
    float* W1T = (float*)d_ws;                    // 64 KB
    float* aug = (float*)d_ws + 16384;            // bs*272 floats
    const int bs = in_sizes[0] / 32;

    const size_t need = 65536 + (size_t)bs * 272 * 4;
    const int solveInMain = (ws_size < need) ? 1 : 0;

    hipFuncSetAttribute((const void*)lnn_kernel,
                        hipFuncAttributeMaxDynamicSharedMemorySize, SMEM_BYTES);
    w1_transpose<<<dim3(64), dim3(256), 0, stream>>>(W1, W1T);
    lnn_kernel<<<dim3(bs), dim3(256), SMEM_BYTES, stream>>>(x, W1, W1T, b1, W2, b2, W3,
                                                            out, aug, solveInMain);
    if (!solveInMain)
        lnn_solve<<<dim3(bs/4), dim3(256), SOLVE_SMEM_BYTES, stream>>>(aug, out);
}

// Round 4
// 4771.547 us; speedup vs baseline: 1.5334x; 1.0130x over previous
//
#include <hip/hip_runtime.h>
#include <math.h>

// LNN: BS=16384, d=32 (n=16), HID=512. All fp32.
// H = W1 D1 W1^T + M D2 M^T,  M = (W1^T diag(s1)) W2,  jac = W1 (s1*u),
// u = W2 (W3*s2), e1 = u(1-s1)/s1 so term1 = ws1T^T diag(e1) ws1T.
// out[:, :16] = qd = x[:,16:]; out[:,16:] = pinv(A) rhs  (fp64 Jacobi eig, JAX rcond).
//
// R4: VALU-issue attack. Main is instruction-issue-bound (VALUBusy 85%).
//  - P2 GEMM inner loop rewritten with v_pk_fma_f32 (VOP3P packed fp32 FMA,
//    2 IEEE FMAs/instr). op_sel/op_sel_hi broadcast the A scalar to both
//    halves -> zero splat moves. Per-element FMA chains unchanged -> bit-identical.
//  - z2 accumulation packed too (h1 read as pairs, lo/hi broadcast by j parity).
//  - term2 (P7) moved directly after P2: acc's 64 regs die before P3/P4/P5.
//  - P5 reads (c5,c5+1) as one ds_read_b64.
// R2/R3: split solve kernel (one wave/sample, 8 blocks/CU) unchanged.

#define NSWEEP 5
#define JAX_RCOND 1.9073486e-5   // 10 * 16 * eps_f32

#define MQS 132                   // M quarter row stride (floats), 33 float4s

// LDS float offsets (main)
#define OFF_R    0                 // wsQ[128][32] / MQ[32][132] / (fallback) fp64 ws
#define R_FLOATS 4224
#define OFF_S1   (OFF_R + R_FLOATS)
#define OFF_H1   (OFF_S1+512)      // h1, later e1
#define OFF_G2   (OFF_H1+512)      // g2, later jac partials [16][16]
#define OFF_D2   (OFF_G2+512)
#define OFF_U    (OFF_D2+512)
#define OFF_X    (OFF_U+512)
#define OFF_JAC  (OFF_X+32)
#define OFF_T1   (OFF_JAC+16)      // [16][33]
#define OFF_T2   (OFF_T1+528)      // [16][33]
#define OFF_AUG  (OFF_T2+528)      // [16][17]
#define SMEM_FLOATS (OFF_AUG+272)
#define SMEM_BYTES  (SMEM_FLOATS*4)   // 32640 B -> 4 blocks/CU

// solve kernel: 592 doubles per wave, 4 waves/block
#define SOLVE_WAVE_DBL 592
#define SOLVE_SMEM_BYTES (4*SOLVE_WAVE_DBL*8)   // 18944 B -> 8 blocks/CU

typedef float f2 __attribute__((ext_vector_type(2)));
typedef float f4 __attribute__((ext_vector_type(4)));

// c.lo += a.lo*b.lo; c.hi += a.lo*b.hi   (broadcast a.lo to both lanes)
__device__ __forceinline__ void pk_lo(f2& c, f2 a, f2 b) {
    asm("v_pk_fma_f32 %0, %1, %2, %0 op_sel:[0,0,0] op_sel_hi:[0,1,1]"
        : "+v"(c) : "v"(a), "v"(b));
}
// c.lo += a.hi*b.lo; c.hi += a.hi*b.hi   (broadcast a.hi to both lanes)
__device__ __forceinline__ void pk_hi(f2& c, f2 a, f2 b) {
    asm("v_pk_fma_f32 %0, %1, %2, %0 op_sel:[1,0,0] op_sel_hi:[1,1,1]"
        : "+v"(c) : "v"(a), "v"(b));
}

__device__ __forceinline__ void pairpq(int r, int m, int& p, int& q) {
    p = (m == 0) ? 0 : 1 + (m - 1 + r) % 15;
    q = 1 + (14 - m + r) % 15;
}

__device__ __forceinline__ void wave_fence() {
    __builtin_amdgcn_wave_barrier();
    __builtin_amdgcn_s_waitcnt(0);     // drain vm/exp/lgkm; DS ops of a wave retire in order
    __builtin_amdgcn_wave_barrier();
}

// Shared fp64 Jacobi pinv solve: one wave, lane-indexed, private LDS region.
// Arithmetic and order IDENTICAL to the original in-kernel P9.
__device__ __forceinline__ void jacobi_solve_wave(
    const float* __restrict__ gaug, double* __restrict__ ws,
    float* __restrict__ outp, int lane)
{
    double* Ad  = ws;                // [16][17]
    double* Vd  = Ad + 272;          // [16][17]
    double* c8  = Vd + 272;          // [8]
    double* sn8 = c8 + 8;            // [8]
    double* il  = sn8 + 8;           // [16]
    double* yv  = il + 16;           // [16]

    for (int idx = lane; idx < 272; idx += 64) {
        const int r = idx / 17, c = idx - r*17;
        double a = 0.0;
        if (c < 16) a = 0.5 * ((double)gaug[r*17 + c] + (double)gaug[c*17 + r]);
        Ad[idx] = a;
        Vd[idx] = (c < 16 && r == c) ? 1.0 : 0.0;
    }
    wave_fence();

    for (int sweep = 0; sweep < NSWEEP; ++sweep) {
        for (int rr = 0; rr < 15; ++rr) {
            if (lane < 8) {
                int p, q; pairpq(rr, lane, p, q);
                const double app = Ad[p*17 + p], aqq = Ad[q*17 + q], apq = Ad[p*17 + q];
                double cc = 1.0, ss = 0.0;
                if (apq != 0.0) {
                    const double tau = (aqq - app) / (2.0 * apq);
                    const double tt = ((tau >= 0.0) ? 1.0 : -1.0) / (fabs(tau) + sqrt(1.0 + tau*tau));
                    cc = 1.0 / sqrt(1.0 + tt*tt);
                    ss = tt * cc;
                }
                c8[lane] = cc; sn8[lane] = ss;
            }
            wave_fence();
            #pragma unroll
            for (int k = 0; k < 2; ++k) {      // rows: A <- J^T A (128 items)
                const int id = lane + 64*k;
                const int m = id >> 4, j = id & 15;
                int p, q; pairpq(rr, m, p, q);
                const double cc = c8[m], ss = sn8[m];
                const double ap = Ad[p*17 + j], aq = Ad[q*17 + j];
                Ad[p*17 + j] = cc*ap - ss*aq;
                Ad[q*17 + j] = ss*ap + cc*aq;
            }
            #pragma unroll
            for (int k = 0; k < 2; ++k) {      // V <- V J (128 items, disjoint array)
                const int id = lane + 64*k;
                const int m = id >> 4, i = id & 15;
                int p, q; pairpq(rr, m, p, q);
                const double cc = c8[m], ss = sn8[m];
                const double vp = Vd[i*17 + p], vq = Vd[i*17 + q];
                Vd[i*17 + p] = cc*vp - ss*vq;
                Vd[i*17 + q] = ss*vp + cc*vq;
            }
            wave_fence();
            #pragma unroll
            for (int k = 0; k < 2; ++k) {      // cols: A <- A J (128 items)
                const int id = lane + 64*k;
                const int m = id >> 4, i = id & 15;
                int p, q; pairpq(rr, m, p, q);
                const double cc = c8[m], ss = sn8[m];
                const double ap = Ad[i*17 + p], aq = Ad[i*17 + q];
                Ad[i*17 + p] = cc*ap - ss*aq;
                Ad[i*17 + q] = ss*ap + cc*aq;
            }
            wave_fence();
        }
    }

    if (lane == 0) {
        double mx = 0.0;
        #pragma unroll
        for (int i = 0; i < 16; ++i) mx = fmax(mx, fabs(Ad[i*17 + i]));
        const double cut = JAX_RCOND * mx;
        #pragma unroll
        for (int i = 0; i < 16; ++i) {
            const double l = Ad[i*17 + i];
            il[i] = (fabs(l) > cut) ? (1.0 / l) : 0.0;
        }
    }
    wave_fence();

    if (lane < 16) {
        double a = 0.0;
        #pragma unroll
        for (int r = 0; r < 16; ++r) a += Vd[r*17 + lane] * (double)gaug[r*17 + 16];
        yv[lane] = a;
    }
    wave_fence();

    if (lane < 16) {
        double a = 0.0;
        #pragma unroll
        for (int i = 0; i < 16; ++i) a += Vd[lane*17 + i] * (il[i] * yv[i]);
        outp[lane] = (float)a;
    }
}

// Pre-kernel: W1T[j*32+i] = W1[i*512+j]   (64 KB, L2-resident afterwards)
extern "C" __global__ void w1_transpose(const float* __restrict__ W1,
                                        float* __restrict__ W1T) {
    const int t = blockIdx.x * 256 + threadIdx.x;   // t = j*32 + i
    W1T[t] = W1[(t & 31) * 512 + (t >> 5)];
}

extern "C" __global__ __launch_bounds__(256, 4)
void lnn_kernel(const float* __restrict__ x,
                const float* __restrict__ W1,
                const float* __restrict__ W1T,
                const float* __restrict__ b1,
                const float* __restrict__ W2, const float* __restrict__ b2,
                const float* __restrict__ W3,
                float* __restrict__ out,
                float* __restrict__ aug_g,
                const int solveInMain)
{
    const int b = blockIdx.x;
    const int t = threadIdx.x;
    const int lane = t & 63;
    const int w = t >> 6;

    extern __shared__ float sm[];
    float* s_ws  = sm + OFF_R;    // wsQ[128][32] (quarter of ws1T, s1-scaled)
    float* s_Mq  = sm + OFF_R;    // MQ[32][132] (quarter of M, overlays wsQ)
    float* s_s1  = sm + OFF_S1;
    float* s_h1  = sm + OFF_H1;   // h1 -> e1
    float* s_g2  = sm + OFF_G2;   // g2 -> jac partials
    float* s_d2  = sm + OFF_D2;
    float* s_u   = sm + OFF_U;
    float* s_x   = sm + OFF_X;
    float* s_jac = sm + OFF_JAC;
    float* s_T1  = sm + OFF_T1;
    float* s_T2  = sm + OFF_T2;
    float* s_aug = sm + OFF_AUG;

    // ---- P0: x row; qd half of output ----
    if (t < 32) s_x[t] = x[b*32 + t];
    if (t < 16) out[b*32 + t] = x[b*32 + 16 + t];
    __syncthreads();

    // ---- P1: z1 -> s1, h1 (coalesced W1 row reads) ----
    #pragma unroll
    for (int rep = 0; rep < 2; ++rep) {
        const int j = t + rep*256;
        float z = b1[j];
        #pragma unroll
        for (int i = 0; i < 32; ++i) z = fmaf(s_x[i], W1[i*512 + j], z);
        const float e = expf(-fabsf(z));
        const float s = (z >= 0.f) ? 1.f/(1.f+e) : e/(1.f+e);
        s_s1[j] = s;
        s_h1[j] = fmaxf(z, 0.f) + log1pf(e);
    }

    // ---- P2: GEMM M = ws1 @ W2, quarter-staged A, packed-fp32 FMA inner loop.
    //          Wave w -> cols w*128..; lane: 4 rgrp x 16 cgrp. Fused z2 acc. ----
    const int r0 = (lane >> 4) * 8;
    const int c0 = w*128 + (lane & 15) * 8;

    // acc2[ii][bq] = (M[r0+ii][c0+2bq], M[r0+ii][c0+2bq+1])
    f2 acc2[8][4];
    #pragma unroll
    for (int ii = 0; ii < 8; ++ii)
        #pragma unroll
        for (int bq = 0; bq < 4; ++bq) acc2[ii][bq] = (f2){0.f, 0.f};

    f2 zacc2[4];
    {
        const f4 bz0 = *(const f4*)(b2 + c0);
        const f4 bz1 = *(const f4*)(b2 + c0 + 4);
        zacc2[0] = __builtin_shufflevector(bz0, bz0, 0, 1);
        zacc2[1] = __builtin_shufflevector(bz0, bz0, 2, 3);
        zacc2[2] = __builtin_shufflevector(bz1, bz1, 0, 1);
        zacc2[3] = __builtin_shufflevector(bz1, bz1, 2, 3);
    }

    const f4* W2v4  = (const f4*)W2;
    const f4* W1Tv4 = (const f4*)W1T;
    const int cq = c0 >> 2;

    for (int q = 0; q < 4; ++q) {
        __syncthreads();   // q=0: covers P1 s1/h1 writes; q>0: wsQ reads done
        // restage wsQ = W1T[quarter] * s1  (coalesced f4 loads, conflict-free stores)
        #pragma unroll
        for (int r = 0; r < 4; ++r) {
            const int f = r*256 + t;               // f4 index within quarter
            f4 v = W1Tv4[q*1024 + f];
            const float s = s_s1[q*128 + (f >> 3)];
            v.x*=s; v.y*=s; v.z*=s; v.w*=s;
            ((f4*)s_ws)[f] = v;
        }
        __syncthreads();

        #pragma unroll 2
        for (int jj = 0; jj < 128; jj += 2) {
            const int j0 = q*128 + jj;
            const f2 h2 = *(const f2*)(s_h1 + j0);     // (h1[j0], h1[j0+1])
            #pragma unroll
            for (int par = 0; par < 2; ++par) {        // j0 (even), j0+1 (odd)
                const int j = j0 + par;
                const f4 bb0 = W2v4[j*128 + cq];
                const f4 bb1 = W2v4[j*128 + cq + 1];
                const f4 a0 = *(const f4*)(s_ws + (jj+par)*32 + r0);
                const f4 a1 = *(const f4*)(s_ws + (jj+par)*32 + r0 + 4);
                f2 bP[4], aP[4];
                bP[0] = __builtin_shufflevector(bb0, bb0, 0, 1);
                bP[1] = __builtin_shufflevector(bb0, bb0, 2, 3);
                bP[2] = __builtin_shufflevector(bb1, bb1, 0, 1);
                bP[3] = __builtin_shufflevector(bb1, bb1, 2, 3);
                aP[0] = __builtin_shufflevector(a0, a0, 0, 1);
                aP[1] = __builtin_shufflevector(a0, a0, 2, 3);
                aP[2] = __builtin_shufflevector(a1, a1, 0, 1);
                aP[3] = __builtin_shufflevector(a1, a1, 2, 3);
                #pragma unroll
                for (int p = 0; p < 4; ++p) {
                    #pragma unroll
                    for (int bq = 0; bq < 4; ++bq) {
                        pk_lo(acc2[2*p  ][bq], aP[p], bP[bq]);   // av[2p]
                        pk_hi(acc2[2*p+1][bq], aP[p], bP[bq]);   // av[2p+1]
                    }
                }
                if (par == 0) {
                    #pragma unroll
                    for (int bq = 0; bq < 4; ++bq) pk_lo(zacc2[bq], h2, bP[bq]);
                } else {
                    #pragma unroll
                    for (int bq = 0; bq < 4; ++bq) pk_hi(zacc2[bq], h2, bP[bq]);
                }
            }
        }
    }

    // z2 -> g2, d2 for own 8 cols
    {
        const float4 w30 = *(const float4*)(W3 + c0);
        const float4 w31 = *(const float4*)(W3 + c0 + 4);
        const float w3v[8] = {w30.x,w30.y,w30.z,w30.w,w31.x,w31.y,w31.z,w31.w};
        #pragma unroll
        for (int kk = 0; kk < 8; ++kk) {
            const float z = (kk & 1) ? zacc2[kk>>1].y : zacc2[kk>>1].x;
            const float e = expf(-fabsf(z));
            const float sg = (z >= 0.f) ? 1.f/(1.f+e) : e/(1.f+e);
            s_g2[c0+kk] = w3v[kk] * sg;
            s_d2[c0+kk] = w3v[kk] * sg * (1.f - sg);
        }
    }
    __syncthreads();

    const int i5 = 16 + (t >> 4);
    const int c5 = 2 * (t & 15);

    // ---- P7 (moved early): term2 = M D2 M^T; acc2 dies here ----
    {
        float h0 = 0.f, h1v = 0.f;
        const float4* d2v = (const float4*)s_d2;
        for (int p = 0; p < 4; ++p) {
            if (w == p) {   // wave p owns cols [p*128, p*128+128) in registers
                #pragma unroll
                for (int ii = 0; ii < 8; ++ii) {
                    float* rp = s_Mq + (r0+ii)*MQS + (lane & 15)*8;
                    *(float4*)(rp)     = make_float4(acc2[ii][0].x, acc2[ii][0].y,
                                                     acc2[ii][1].x, acc2[ii][1].y);
                    *(float4*)(rp + 4) = make_float4(acc2[ii][2].x, acc2[ii][2].y,
                                                     acc2[ii][3].x, acc2[ii][3].y);
                }
            }
            __syncthreads();
            const float4* Mi = (const float4*)(s_Mq + i5*MQS);
            const float4* Ma = (const float4*)(s_Mq + c5*MQS);
            const float4* Mb = (const float4*)(s_Mq + (c5+1)*MQS);
            for (int qq = 0; qq < 32; ++qq) {
                const float4 d  = d2v[p*32 + qq];
                const float4 mi = Mi[qq];
                const float4 ma = Ma[qq];
                const float4 mb = Mb[qq];
                float tt;
                tt = mi.x*d.x; h0 = fmaf(tt, ma.x, h0); h1v = fmaf(tt, mb.x, h1v);
                tt = mi.y*d.y; h0 = fmaf(tt, ma.y, h0); h1v = fmaf(tt, mb.y, h1v);
                tt = mi.z*d.z; h0 = fmaf(tt, ma.z, h0); h1v = fmaf(tt, mb.z, h1v);
                tt = mi.w*d.w; h0 = fmaf(tt, ma.w, h0); h1v = fmaf(tt, mb.w, h1v);
            }
            __syncthreads();   // reads done before next pass overwrites MQ
        }
        s_T2[(i5-16)*33 + c5]     = h0;
        s_T2[(i5-16)*33 + c5 + 1] = h1v;
    }

    // ---- P3: u[j] = W2[j,:] . g2 (wave w -> j in [w*128, w*128+128)),
    //          2-way ILP on the shuffle-reduce chains ----
    {
        float g2f[8];
        {
            const float4 ga = *(const float4*)(s_g2 + lane*8);
            const float4 gb = *(const float4*)(s_g2 + lane*8 + 4);
            g2f[0]=ga.x; g2f[1]=ga.y; g2f[2]=ga.z; g2f[3]=ga.w;
            g2f[4]=gb.x; g2f[5]=gb.y; g2f[6]=gb.z; g2f[7]=gb.w;
        }
        for (int jj = 0; jj < 64; ++jj) {
            const int j0 = w*128 + jj;
            const int j1 = j0 + 64;
            const float4 ra0 = *(const float4*)(W2 + j0*512 + lane*8);
            const float4 rb0 = *(const float4*)(W2 + j0*512 + lane*8 + 4);
            const float4 ra1 = *(const float4*)(W2 + j1*512 + lane*8);
            const float4 rb1 = *(const float4*)(W2 + j1*512 + lane*8 + 4);
            float p0 = ra0.x*g2f[0];
            p0 = fmaf(ra0.y, g2f[1], p0); p0 = fmaf(ra0.z, g2f[2], p0); p0 = fmaf(ra0.w, g2f[3], p0);
            p0 = fmaf(rb0.x, g2f[4], p0); p0 = fmaf(rb0.y, g2f[5], p0);
            p0 = fmaf(rb0.z, g2f[6], p0); p0 = fmaf(rb0.w, g2f[7], p0);
            float p1 = ra1.x*g2f[0];
            p1 = fmaf(ra1.y, g2f[1], p1); p1 = fmaf(ra1.z, g2f[2], p1); p1 = fmaf(ra1.w, g2f[3], p1);
            p1 = fmaf(rb1.x, g2f[4], p1); p1 = fmaf(rb1.y, g2f[5], p1);
            p1 = fmaf(rb1.z, g2f[6], p1); p1 = fmaf(rb1.w, g2f[7], p1);
            #pragma unroll
            for (int off = 32; off >= 1; off >>= 1) {
                p0 += __shfl_xor(p0, off);
                p1 += __shfl_xor(p1, off);
            }
            if (lane == 0) { s_u[j0] = p0; s_u[j1] = p1; }
        }
    }
    __syncthreads();

    // ---- P4e: e1 = u(1-s1)/s1 into s_h1 (h1 dead) ----
    #pragma unroll
    for (int rep = 0; rep < 2; ++rep) {
        const int j = t + rep*256;
        const float uj = s_u[j], s = s_s1[j];
        s_h1[j] = uj * (1.f - s) / s;
    }

    // ---- P4/P5 quarter-staged: jac partials + term1 ----
    float jacp = 0.f, t1a = 0.f, t1b = 0.f;

    for (int q = 0; q < 4; ++q) {
        __syncthreads();   // q=0: e1 writes + P7 MQ reads done; q>0: wsQ reads done
        #pragma unroll
        for (int r = 0; r < 4; ++r) {
            const int f = r*256 + t;
            f4 v = W1Tv4[q*1024 + f];
            const float s = s_s1[q*128 + (f >> 3)];
            v.x*=s; v.y*=s; v.z*=s; v.w*=s;
            ((f4*)s_ws)[f] = v;
        }
        __syncthreads();

        // P4 partial: quarter q's segs (4q..4q+3) live entirely in wave q
        if (w == q) {
            const int i  = t & 15;
            const int jb = (lane >> 4) * 32;       // local j base
            #pragma unroll 8
            for (int jj = 0; jj < 32; ++jj)
                jacp = fmaf(s_ws[(jb+jj)*32 + i], s_u[q*128 + jb + jj], jacp);
        }

        // P5 partial: term1 over this quarter (all threads)
        #pragma unroll 4
        for (int jj = 0; jj < 128; ++jj) {
            const float e   = s_h1[q*128 + jj];
            const float wsi = s_ws[jj*32 + i5];
            const f2 wc = *(const f2*)(s_ws + jj*32 + c5);   // ds_read_b64 pair
            const float tt  = wsi * e;
            t1a = fmaf(tt, wc.x, t1a);
            t1b = fmaf(tt, wc.y, t1b);
        }
    }
    s_T1[(i5-16)*33 + c5]     = t1a;
    s_T1[(i5-16)*33 + c5 + 1] = t1b;
    s_g2[(t>>4)*16 + (t&15)]  = jacp;   // g2 dead after P3; reuse for jac partials
    __syncthreads();

    // ---- fold jac + P8 A-part (disjoint) ----
    if (t < 16) {
        float p = 0.f;
        #pragma unroll
        for (int seg = 0; seg < 16; ++seg) p += s_g2[seg*16 + t];
        s_jac[t] = p;
    }
    {
        const int r = t >> 4, c = t & 15;
        s_aug[r*17 + c] = s_T1[r*33 + 16 + c] + s_T2[r*33 + 16 + c];
    }
    __syncthreads();

    // ---- P8 rhs (needs s_jac) ----
    if (t < 16) {
        float p = s_jac[t];
        #pragma unroll
        for (int c = 0; c < 16; ++c)
            p -= (s_T1[t*33 + c] + s_T2[t*33 + c]) * s_x[16 + c];
        s_aug[t*17 + 16] = p;
    }
    __syncthreads();

    if (!solveInMain) {
        // ---- P8b: store aug (272 floats with 256 threads: body + 16-elem tail) ----
        aug_g[b*272 + t] = s_aug[t];
        if (t < 16) aug_g[b*272 + 256 + t] = s_aug[256 + t];
        return;
    }

    // ---- Fallback P9: single-wave fp64 Jacobi (only if workspace too small) ----
    if (w != 0) return;
    jacobi_solve_wave(s_aug, (double*)sm, out + b*32 + 16, lane);
}

extern "C" __global__ __launch_bounds__(256, 8)
void lnn_solve(const float* __restrict__ aug_g, float* __restrict__ out)
{
    const int t = threadIdx.x;
    const int lane = t & 63;
    const int w = t >> 6;
    const int b = blockIdx.x * 4 + w;

    extern __shared__ double dsm[];
    jacobi_solve_wave(aug_g + b*272, dsm + w*SOLVE_WAVE_DBL, out + b*32 + 16, lane);
}

extern "C" void kernel_launch(void* const* d_in, const int* in_sizes, int n_in,
                              void* d_out, int out_size, void* d_ws, size_t ws_size,
                              hipStream_t stream) {
    const float* x  = (const float*)d_in[0];
    const float* W1 = (const float*)d_in[1];
    const float* b1 = (const float*)d_in[2];
    const float* W2 = (const float*)d_in[3];
    const float* b2 = (const float*)d_in[4];
    const float* W3 = (const float*)d_in[5];
    float* out = (float*)d_out;
    float* W1T = (float*)d_ws;                    // 64 KB
    float* aug = (float*)d_ws + 16384;            // bs*272 floats
    const int bs = in_sizes[0] / 32;

    const size_t need = 65536 + (size_t)bs * 272 * 4;
    const int solveInMain = (ws_size < need) ? 1 : 0;

    hipFuncSetAttribute((const void*)lnn_kernel,
                        hipFuncAttributeMaxDynamicSharedMemorySize, SMEM_BYTES);
    w1_transpose<<<dim3(64), dim3(256), 0, stream>>>(W1, W1T);
    lnn_kernel<<<dim3(bs), dim3(256), SMEM_BYTES, stream>>>(x, W1, W1T, b1, W2, b2, W3,
                                                            out, aug, solveInMain);
    if (!solveInMain)
        lnn_solve<<<dim3(bs/4), dim3(256), SOLVE_SMEM_BYTES, stream>>>(aug, out);
}